// Round 2
// baseline (1407.385 us; speedup 1.0000x reference)
//
#include <hip/hip_runtime.h>
#include <stdint.h>

#define M_DIM 8192
#define K_DIM 4096
#define N_DIM 16384

#define BM 128
#define BN 128
#define BK 64

typedef int v4i __attribute__((ext_vector_type(4)));

// ---------------------------------------------------------------------------
// Kernel 1: per-row dynamic int8 quantization of activations
// one block (256 threads) per row; K=4096 -> 16 floats/thread kept in regs
// ---------------------------------------------------------------------------
__global__ __launch_bounds__(256) void quantize_x(const float* __restrict__ x,
                                                  int8_t* __restrict__ qx,
                                                  float* __restrict__ sx) {
    const int row = blockIdx.x;
    const int t = threadIdx.x;
    const float4* xr = reinterpret_cast<const float4*>(x + (size_t)row * K_DIM);

    float4 v[4];
    float amax = 0.0f;
#pragma unroll
    for (int i = 0; i < 4; ++i) {
        v[i] = xr[i * 256 + t];
        amax = fmaxf(amax, fmaxf(fmaxf(fabsf(v[i].x), fabsf(v[i].y)),
                                 fmaxf(fabsf(v[i].z), fabsf(v[i].w))));
    }
    // wave (64-lane) butterfly reduce
#pragma unroll
    for (int off = 32; off >= 1; off >>= 1)
        amax = fmaxf(amax, __shfl_xor(amax, off));

    __shared__ float wmax[4];
    const int wid = t >> 6, lane = t & 63;
    if (lane == 0) wmax[wid] = amax;
    __syncthreads();
    amax = fmaxf(fmaxf(wmax[0], wmax[1]), fmaxf(wmax[2], wmax[3]));

    const float scale = amax / 127.0f;  // match reference: max|x| / 127.0
    if (t == 0) sx[row] = scale;

    int* qr = reinterpret_cast<int*>(qx + (size_t)row * K_DIM);
#pragma unroll
    for (int i = 0; i < 4; ++i) {
        const int q0 = (int)rintf(v[i].x / scale);
        const int q1 = (int)rintf(v[i].y / scale);
        const int q2 = (int)rintf(v[i].z / scale);
        const int q3 = (int)rintf(v[i].w / scale);
        qr[i * 256 + t] = (q0 & 0xff) | ((q1 & 0xff) << 8) |
                          ((q2 & 0xff) << 16) | ((q3 & 0xff) << 24);
    }
}

// ---------------------------------------------------------------------------
// Kernel 2: weight int32 -> int8 pack (values already in [-127,127])
// each thread: one int4 load (4 elems) -> one packed dword store
// ---------------------------------------------------------------------------
__global__ __launch_bounds__(256) void quantize_w(const int* __restrict__ w,
                                                  int8_t* __restrict__ qw) {
    const size_t i = (size_t)blockIdx.x * 256 + threadIdx.x;
    const int4 v = reinterpret_cast<const int4*>(w)[i];
    reinterpret_cast<int*>(qw)[i] = (v.x & 0xff) | ((v.y & 0xff) << 8) |
                                    ((v.z & 0xff) << 16) | ((v.w & 0xff) << 24);
}

// ---------------------------------------------------------------------------
// Kernel 3: int8 GEMM, C[m,n] = sum_k qx[m,k]*qw[n,k], fused dequant epilogue
// 128x128 tile, BK=64, 4 waves (2x2), wave tile 64x64 = 4x4 of 16x16x64 MFMA
// double-buffered LDS, global_load_lds width-16 staging, linear [row][64B]
// ---------------------------------------------------------------------------
#define GLOAD16(gsrc, ldst)                                                     \
    __builtin_amdgcn_global_load_lds(                                           \
        (const __attribute__((address_space(1))) void*)(gsrc),                  \
        (__attribute__((address_space(3))) void*)(ldst), 16, 0, 0)

__global__ __launch_bounds__(256) void gemm_i8(
    const int8_t* __restrict__ qx, const int8_t* __restrict__ qw,
    const float* __restrict__ sx, const float* __restrict__ wsc,
    const float* __restrict__ bias, float* __restrict__ out) {
    __shared__ int8_t lds[2][2][BM * BK];  // [buf][A=0/B=1][128 rows x 64 B]

    const int tid = threadIdx.x;
    const int lane = tid & 63;
    const int wid = tid >> 6;
    const int wr = wid >> 1;   // wave row (0..1)
    const int wc = wid & 1;    // wave col (0..1)

    const int bid = blockIdx.x;
    const int bn = bid % (N_DIM / BN);  // 0..127
    const int bm = bid / (N_DIM / BN);  // 0..63

    const int8_t* aBase = qx + (size_t)(bm * BM) * K_DIM;
    const int8_t* bBase = qw + (size_t)(bn * BN) * K_DIM;

    // staging address components (per-thread global, wave-uniform LDS dest)
    const int srow0 = tid >> 2;          // round 0 row (0..63)
    const int scol = (tid & 3) * 16;     // byte offset within 64B row

    v4i acc[4][4] = {};

    // prologue: stage k-tile 0 into buf 0
    {
        const int8_t* aS = aBase;
        const int8_t* bS = bBase;
#pragma unroll
        for (int r = 0; r < 2; ++r) {
            const int row = srow0 + r * 64;
            GLOAD16(aS + (size_t)row * K_DIM + scol, &lds[0][0][(r * 256 + wid * 64) * 16]);
            GLOAD16(bS + (size_t)row * K_DIM + scol, &lds[0][1][(r * 256 + wid * 64) * 16]);
        }
    }
    __syncthreads();

    int cur = 0;
    const int NT = K_DIM / BK;  // 64
    for (int kt = 0; kt < NT; ++kt) {
        // prefetch next k-tile into the other buffer
        if (kt + 1 < NT) {
            const int8_t* aS = aBase + (size_t)(kt + 1) * BK;
            const int8_t* bS = bBase + (size_t)(kt + 1) * BK;
#pragma unroll
            for (int r = 0; r < 2; ++r) {
                const int row = srow0 + r * 64;
                GLOAD16(aS + (size_t)row * K_DIM + scol,
                        &lds[cur ^ 1][0][(r * 256 + wid * 64) * 16]);
                GLOAD16(bS + (size_t)row * K_DIM + scol,
                        &lds[cur ^ 1][1][(r * 256 + wid * 64) * 16]);
            }
        }

        // LDS -> fragments
        v4i af[4], bf[4];
#pragma unroll
        for (int mi = 0; mi < 4; ++mi)
            af[mi] = *(const v4i*)&lds[cur][0][(wr * 64 + mi * 16 + (lane & 15)) * BK +
                                               (lane >> 4) * 16];
#pragma unroll
        for (int ni = 0; ni < 4; ++ni)
            bf[ni] = *(const v4i*)&lds[cur][1][(wc * 64 + ni * 16 + (lane & 15)) * BK +
                                               (lane >> 4) * 16];

#pragma unroll
        for (int mi = 0; mi < 4; ++mi)
#pragma unroll
            for (int ni = 0; ni < 4; ++ni)
                acc[mi][ni] =
                    __builtin_amdgcn_mfma_i32_16x16x64_i8(af[mi], bf[ni], acc[mi][ni], 0, 0, 0);

        __syncthreads();
        cur ^= 1;
    }

    // epilogue: dequant + bias, scalar f32 stores (4 rows x 16 cols per frag)
    float wsv[4], bv[4];
#pragma unroll
    for (int ni = 0; ni < 4; ++ni) {
        const int col = bn * BN + wc * 64 + ni * 16 + (lane & 15);
        wsv[ni] = wsc[col];
        bv[ni] = bias[col];
    }
#pragma unroll
    for (int mi = 0; mi < 4; ++mi) {
#pragma unroll
        for (int j = 0; j < 4; ++j) {
            const int row = bm * BM + wr * 64 + mi * 16 + (lane >> 4) * 4 + j;
            const float s = sx[row];
            float* orow = out + (size_t)row * N_DIM;
#pragma unroll
            for (int ni = 0; ni < 4; ++ni) {
                const int col = bn * BN + wc * 64 + ni * 16 + (lane & 15);
                orow[col] = (float)acc[mi][ni][j] * s * wsv[ni] + bv[ni];
            }
        }
    }
}

// ---------------------------------------------------------------------------
extern "C" void kernel_launch(void* const* d_in, const int* in_sizes, int n_in,
                              void* d_out, int out_size, void* d_ws, size_t ws_size,
                              hipStream_t stream) {
    const float* x = (const float*)d_in[0];
    const int* wq = (const int*)d_in[1];
    const float* wsc = (const float*)d_in[2];
    const float* bias = (const float*)d_in[3];
    float* out = (float*)d_out;

    int8_t* qw = (int8_t*)d_ws;                       // 64 MB
    int8_t* qx = qw + (size_t)N_DIM * K_DIM;          // 32 MB
    float* sx = (float*)(qx + (size_t)M_DIM * K_DIM); // 32 KB

    quantize_w<<<(N_DIM * (size_t)K_DIM) / (4 * 256), 256, 0, stream>>>(wq, qw);
    quantize_x<<<M_DIM, 256, 0, stream>>>(x, qx, sx);
    gemm_i8<<<(M_DIM / BM) * (N_DIM / BN), 256, 0, stream>>>(qx, qw, sx, wsc, bias, out);
}